// Round 5
// baseline (3243.049 us; speedup 1.0000x reference)
//
#include <hip/hip_runtime.h>
#include <hip/hip_cooperative_groups.h>
#include <cstdint>
#include <cstddef>

#define N_NODES 50000
#define N_EDGES 800000
#define DIM_H   128
#define DIM_P   64     // propagation width after commuting W3
#define DIM_OUT 1000
#define OUT_PAD 1024   // padded col count for MFMA tiles
#define KHOPS   10
#define BN_EPS  1e-5f

namespace cg = cooperative_groups;

static inline int ceil_div(int a, int b) { return (a + b - 1) / b; }

typedef short  bf16x8  __attribute__((ext_vector_type(8)));
typedef float  floatx4 __attribute__((ext_vector_type(4)));

__device__ __forceinline__ unsigned short f2bf_rne(float v) {
    unsigned int u = __float_as_uint(v);
    return (unsigned short)((u + 0x7fffu + ((u >> 16) & 1u)) >> 16);
}

// ---------------- softmax over att[11] ----------------
__global__ void softmax11(const float* __restrict__ att, float* __restrict__ w) {
    if (threadIdx.x == 0) {
        float mx = att[0];
        for (int i = 1; i < KHOPS + 1; ++i) mx = fmaxf(mx, att[i]);
        float e[KHOPS + 1];
        float s = 0.f;
        for (int i = 0; i < KHOPS + 1; ++i) { e[i] = expf(att[i] - mx); s += e[i]; }
        for (int i = 0; i < KHOPS + 1; ++i) w[i] = e[i] / s;
    }
}

// ---------------- CSR build ----------------
__global__ void count_deg(const int* __restrict__ dst, int* __restrict__ deg, int ne) {
    int i = blockIdx.x * blockDim.x + threadIdx.x;
    if (i < ne) atomicAdd(&deg[dst[i]], 1);
}

// local inclusive scan per 1024-block (shuffle-based, 3 barriers)
__global__ __launch_bounds__(1024) void scan_local(const int* __restrict__ deg,
                                                   int* __restrict__ row_ptr,
                                                   int* __restrict__ bsums, int n) {
    __shared__ int wsum[16];
    const int i = blockIdx.x * 1024 + threadIdx.x;
    const int lane = threadIdx.x & 63, w = threadIdx.x >> 6;
    int v = (i < n) ? deg[i] : 0;
    int s = v;
#pragma unroll
    for (int d = 1; d < 64; d <<= 1) {
        int t = __shfl_up(s, d, 64);
        if (lane >= d) s += t;
    }
    if (lane == 63) wsum[w] = s;
    __syncthreads();
    if (w == 0) {
        int x = (lane < 16) ? wsum[lane] : 0;
#pragma unroll
        for (int d = 1; d < 16; d <<= 1) {
            int t = __shfl_up(x, d, 64);
            if (lane >= d) x += t;
        }
        if (lane < 16) wsum[lane] = x;
    }
    __syncthreads();
    int incl = s + ((w > 0) ? wsum[w - 1] : 0);
    if (i < n) row_ptr[i + 1] = incl;
    if (threadIdx.x == 1023) bsums[blockIdx.x] = incl;
}

// exclusive scan of block sums (nb <= 64), single wave
__global__ void scan_bsums(int* __restrict__ bsums, int nb) {
    int lane = threadIdx.x;
    int v = (lane < nb) ? bsums[lane] : 0;
    int s = v;
#pragma unroll
    for (int d = 1; d < 64; d <<= 1) {
        int t = __shfl_up(s, d, 64);
        if (lane >= d) s += t;
    }
    if (lane < nb) bsums[lane] = s - v;
}

// add block offsets; also derive fill-cursor (exclusive start) in-place in deg
__global__ void scan_finish(int* __restrict__ row_ptr, int* __restrict__ deg,
                            const int* __restrict__ bsums, int n) {
    int i = blockIdx.x * blockDim.x + threadIdx.x;
    if (i < n) {
        int incl = row_ptr[i + 1] + bsums[i >> 10];
        row_ptr[i + 1] = incl;
        deg[i] = incl - deg[i];   // cursor = exclusive prefix
    }
    if (i == 0) row_ptr[0] = 0;
}

__global__ void fill_csr(const int* __restrict__ src, const int* __restrict__ dst,
                         int* __restrict__ cursor, int* __restrict__ col, int ne) {
    int i = blockIdx.x * blockDim.x + threadIdx.x;
    if (i < ne) {
        int d = dst[i];
        int pos = atomicAdd(&cursor[d], 1);
        col[pos] = src[i];
    }
}

// ---------------- fused GEMM: C[n,M] = act(A) @ W (+bias) -------------------
// act(A) row = relu(A*scA+shA)  [if scA]  +  relu(A2*scA2+shA2)  [if A2]
// optional second output C2 = w0p[0] * C  (fused scale_init)
template<int KD, int CPB>
__global__ __launch_bounds__(256) void gemm_fused(
    const float* __restrict__ A,  const float* __restrict__ scA,
    const float* __restrict__ A2, const float* __restrict__ scA2,
    const float* __restrict__ W,  const float* __restrict__ bias,
    float* __restrict__ C, float* __restrict__ C2, const float* __restrict__ w0p,
    int n, int M) {
    constexpr int CG  = CPB / 4;     // col groups per block
    constexpr int RG  = 256 / CG;    // row groups
    constexpr int RPT = 64 / RG;     // rows per thread
    __shared__ float As[64][KD + 4];

    const int tid  = threadIdx.x;
    const int cg   = tid % CG;
    const int rg   = tid / CG;
    const int row0 = blockIdx.x * 64;
    const int col0 = blockIdx.y * CPB + cg * 4;

    constexpr int VECS = 64 * KD / 4;
    for (int i = tid; i < VECS; i += 256) {
        int r  = i / (KD / 4);
        int k4 = (i % (KD / 4)) * 4;
        float4 v = make_float4(0.f, 0.f, 0.f, 0.f);
        int row = row0 + r;
        if (row < n) {
            v = *reinterpret_cast<const float4*>(A + (size_t)row * KD + k4);
            if (scA) {
                float4 sc = *reinterpret_cast<const float4*>(scA + k4);
                float4 sh = *reinterpret_cast<const float4*>(scA + KD + k4);
                v.x = fmaxf(v.x * sc.x + sh.x, 0.f);
                v.y = fmaxf(v.y * sc.y + sh.y, 0.f);
                v.z = fmaxf(v.z * sc.z + sh.z, 0.f);
                v.w = fmaxf(v.w * sc.w + sh.w, 0.f);
            }
            if (A2) {
                float4 u  = *reinterpret_cast<const float4*>(A2 + (size_t)row * KD + k4);
                float4 sc = *reinterpret_cast<const float4*>(scA2 + k4);
                float4 sh = *reinterpret_cast<const float4*>(scA2 + KD + k4);
                v.x += fmaxf(u.x * sc.x + sh.x, 0.f);
                v.y += fmaxf(u.y * sc.y + sh.y, 0.f);
                v.z += fmaxf(u.z * sc.z + sh.z, 0.f);
                v.w += fmaxf(u.w * sc.w + sh.w, 0.f);
            }
        }
        *reinterpret_cast<float4*>(&As[r][k4]) = v;
    }
    __syncthreads();

    if (col0 >= M) return;

    float acc[RPT][4];
#pragma unroll
    for (int r = 0; r < RPT; ++r)
#pragma unroll
        for (int c = 0; c < 4; ++c) acc[r][c] = 0.f;

    for (int k4 = 0; k4 < KD; k4 += 4) {
        float4 w0 = *reinterpret_cast<const float4*>(W + (size_t)(k4 + 0) * M + col0);
        float4 w1 = *reinterpret_cast<const float4*>(W + (size_t)(k4 + 1) * M + col0);
        float4 w2 = *reinterpret_cast<const float4*>(W + (size_t)(k4 + 2) * M + col0);
        float4 w3 = *reinterpret_cast<const float4*>(W + (size_t)(k4 + 3) * M + col0);
#pragma unroll
        for (int r = 0; r < RPT; ++r) {
            float4 a = *reinterpret_cast<const float4*>(&As[rg * RPT + r][k4]);
            acc[r][0] += a.x * w0.x + a.y * w1.x + a.z * w2.x + a.w * w3.x;
            acc[r][1] += a.x * w0.y + a.y * w1.y + a.z * w2.y + a.w * w3.y;
            acc[r][2] += a.x * w0.z + a.y * w1.z + a.z * w2.z + a.w * w3.z;
            acc[r][3] += a.x * w0.w + a.y * w1.w + a.z * w2.w + a.w * w3.w;
        }
    }

    float4 b = make_float4(0.f, 0.f, 0.f, 0.f);
    if (bias) b = *reinterpret_cast<const float4*>(bias + col0);
    const float w0s = C2 ? w0p[0] : 0.f;
#pragma unroll
    for (int r = 0; r < RPT; ++r) {
        int row = row0 + rg * RPT + r;
        if (row < n) {
            float4 o = make_float4(acc[r][0] + b.x, acc[r][1] + b.y,
                                   acc[r][2] + b.z, acc[r][3] + b.w);
            *reinterpret_cast<float4*>(C + (size_t)row * M + col0) = o;
            if (C2) {
                float4 q = make_float4(w0s * o.x, w0s * o.y, w0s * o.z, w0s * o.w);
                *reinterpret_cast<float4*>(C2 + (size_t)row * M + col0) = q;
            }
        }
    }
}

// ---------------- BN column stats (sum, sumsq) in double ----------------
template<int M>
__global__ __launch_bounds__(256) void colstats(const float* __restrict__ Z,
                                                double* __restrict__ st, int n) {
    constexpr int RG = 256 / M;
    const int tid = threadIdx.x;
    const int c = tid % M, rg = tid / M;
    double s = 0.0, ss = 0.0;
    for (int row = blockIdx.x * RG + rg; row < n; row += gridDim.x * RG) {
        float v = Z[(size_t)row * M + c];
        s += v;
        ss += (double)v * (double)v;
    }
    __shared__ double sh[2][256];
    sh[0][tid] = s;
    sh[1][tid] = ss;
    __syncthreads();
    if (rg == 0) {
#pragma unroll
        for (int g = 1; g < RG; ++g) { s += sh[0][c + g * M]; ss += sh[1][c + g * M]; }
        atomicAdd(&st[c], s);
        atomicAdd(&st[M + c], ss);
    }
}

__global__ void bn_finalize(const double* __restrict__ st, const float* __restrict__ g,
                            const float* __restrict__ be, float* __restrict__ scsh,
                            int M, int n) {
    int c = threadIdx.x + blockIdx.x * blockDim.x;
    if (c < M) {
        double m = st[c] / n;
        double v = st[M + c] / n - m * m;
        float scale = g[c] * rsqrtf((float)v + BN_EPS);
        scsh[c]     = scale;
        scsh[M + c] = be[c] - (float)m * scale;
    }
}

// ---------------- ALL K propagation hops, one cooperative kernel -------------
// Same per-node math as the 10-launch version (bit-identical summation order):
// 16 lanes x float4 per 256B neighbor row, 4 lane-groups x 4-deep unroll = 16
// edges in flight; tails at 8/4/1. Persistent waves grid-stride over nodes;
// grid.sync() between hops replaces kernel relaunch.
__global__ __launch_bounds__(256, 4) void propagate_all(
    float* b0, float* b1, float* oacc,
    const int* __restrict__ row_ptr, const int* __restrict__ col,
    const float* __restrict__ wts, int n) {
    cg::grid_group grid = cg::this_grid();
    const int wid  = blockIdx.x * 4 + (threadIdx.x >> 6);
    const int nw   = gridDim.x * 4;
    const int lane = threadIdx.x & 63;
    const int g = lane >> 4;      // neighbor slot 0..3
    const int l = lane & 15;      // feature quad: features l*4 .. l*4+3

    float* cur = b0;
    float* nxt = b1;
    for (int hop = 1; hop <= KHOPS; ++hop) {
        const float w = wts[hop];
        const bool last = (hop == KHOPS);
        for (int node = wid; node < n; node += nw) {
            const int beg = row_ptr[node], end = row_ptr[node + 1];
            float4 acc = make_float4(0.f, 0.f, 0.f, 0.f);
            int e = beg;
            for (; e + 16 <= end; e += 16) {
                int s0 = col[e + g];
                int s1 = col[e + g + 4];
                int s2 = col[e + g + 8];
                int s3 = col[e + g + 12];
                float4 v0 = *reinterpret_cast<const float4*>(cur + (size_t)s0 * DIM_P + l * 4);
                float4 v1 = *reinterpret_cast<const float4*>(cur + (size_t)s1 * DIM_P + l * 4);
                float4 v2 = *reinterpret_cast<const float4*>(cur + (size_t)s2 * DIM_P + l * 4);
                float4 v3 = *reinterpret_cast<const float4*>(cur + (size_t)s3 * DIM_P + l * 4);
                acc.x += (v0.x + v1.x) + (v2.x + v3.x);
                acc.y += (v0.y + v1.y) + (v2.y + v3.y);
                acc.z += (v0.z + v1.z) + (v2.z + v3.z);
                acc.w += (v0.w + v1.w) + (v2.w + v3.w);
            }
            if (e + 8 <= end) {
                int s0 = col[e + g];
                int s1 = col[e + g + 4];
                float4 v0 = *reinterpret_cast<const float4*>(cur + (size_t)s0 * DIM_P + l * 4);
                float4 v1 = *reinterpret_cast<const float4*>(cur + (size_t)s1 * DIM_P + l * 4);
                acc.x += v0.x + v1.x; acc.y += v0.y + v1.y;
                acc.z += v0.z + v1.z; acc.w += v0.w + v1.w;
                e += 8;
            }
            if (e + 4 <= end) {
                int s = col[e + g];
                float4 v = *reinterpret_cast<const float4*>(cur + (size_t)s * DIM_P + l * 4);
                acc.x += v.x; acc.y += v.y; acc.z += v.z; acc.w += v.w;
                e += 4;
            }
            if (e + g < end) {
                int s = col[e + g];
                float4 v = *reinterpret_cast<const float4*>(cur + (size_t)s * DIM_P + l * 4);
                acc.x += v.x; acc.y += v.y; acc.z += v.z; acc.w += v.w;
            }
#pragma unroll
            for (int off = 16; off < 64; off <<= 1) {
                acc.x += __shfl_xor(acc.x, off, 64);
                acc.y += __shfl_xor(acc.y, off, 64);
                acc.z += __shfl_xor(acc.z, off, 64);
                acc.w += __shfl_xor(acc.w, off, 64);
            }
            if (g == 0) {
                size_t o = (size_t)node * DIM_P + l * 4;
                if (!last) *reinterpret_cast<float4*>(nxt + o) = acc;
                float4 t = *reinterpret_cast<const float4*>(oacc + o);
                t.x = fmaf(w, acc.x, t.x); t.y = fmaf(w, acc.y, t.y);
                t.z = fmaf(w, acc.z, t.z); t.w = fmaf(w, acc.w, t.w);
                *reinterpret_cast<float4*>(oacc + o) = t;
            }
        }
        __threadfence();
        grid.sync();
        float* t = cur; cur = nxt; nxt = t;
    }
}

// ---------------- Wout transpose + bf16 convert: WT[c][k] = bf16(W[k][c]) ----
// padded to OUT_PAD rows; pad rows are zero so MFMA tiles past col 999 are inert
__global__ void prep_wout(const float* __restrict__ W, unsigned short* __restrict__ WT) {
    int idx = blockIdx.x * blockDim.x + threadIdx.x;  // idx = c*64 + k
    if (idx < OUT_PAD * DIM_P) {
        int c = idx >> 6, k = idx & 63;
        WT[idx] = (c < DIM_OUT) ? f2bf_rne(W[(size_t)k * DIM_OUT + c]) : (unsigned short)0;
    }
}

// ---------------- bn3 + relu + bf16 convert, once: ABF[row][k] ----------------
__global__ void bn3_relu_bf16(const float* __restrict__ Z, const float* __restrict__ scsh,
                              unsigned short* __restrict__ O) {
    const int total8 = N_NODES * DIM_P / 8;
    int i = blockIdx.x * blockDim.x + threadIdx.x;
    if (i >= total8) return;
    int base = i * 8;
    int c = base & (DIM_P - 1);
    float4 z0 = *reinterpret_cast<const float4*>(Z + base);
    float4 z1 = *reinterpret_cast<const float4*>(Z + base + 4);
    float4 s0 = *reinterpret_cast<const float4*>(scsh + c);
    float4 s1 = *reinterpret_cast<const float4*>(scsh + c + 4);
    float4 h0 = *reinterpret_cast<const float4*>(scsh + DIM_P + c);
    float4 h1 = *reinterpret_cast<const float4*>(scsh + DIM_P + c + 4);
    bf16x8 o;
    o[0] = (short)f2bf_rne(fmaxf(z0.x * s0.x + h0.x, 0.f));
    o[1] = (short)f2bf_rne(fmaxf(z0.y * s0.y + h0.y, 0.f));
    o[2] = (short)f2bf_rne(fmaxf(z0.z * s0.z + h0.z, 0.f));
    o[3] = (short)f2bf_rne(fmaxf(z0.w * s0.w + h0.w, 0.f));
    o[4] = (short)f2bf_rne(fmaxf(z1.x * s1.x + h1.x, 0.f));
    o[5] = (short)f2bf_rne(fmaxf(z1.y * s1.y + h1.y, 0.f));
    o[6] = (short)f2bf_rne(fmaxf(z1.z * s1.z + h1.z, 0.f));
    o[7] = (short)f2bf_rne(fmaxf(z1.w * s1.w + h1.w, 0.f));
    *reinterpret_cast<bf16x8*>(O + base) = o;
}

// ---------------- final GEMM via MFMA: out = ABF @ Wout + bout ----------------
// A-operand = Wout columns (register-resident across row loop), B = node rows.
// Each lane stores float4 of 4 consecutive output columns.
__global__ __launch_bounds__(256, 4) void out_gemm_mfma(
    const unsigned short* __restrict__ ABF, const unsigned short* __restrict__ WT,
    const float* __restrict__ bout, float* __restrict__ out) {
    const int wave = threadIdx.x >> 6;
    const int lane = threadIdx.x & 63;
    const int m    = lane & 15;       // A: out-col within tile; B/D: out-row
    const int quad = lane >> 4;
    const int kb   = quad * 8;
    const int c0   = blockIdx.y * 256 + wave * 64;

    bf16x8 afrag[4][2];
    float4 bias[4];
#pragma unroll
    for (int t = 0; t < 4; ++t) {
        const unsigned short* wrow = WT + (size_t)(c0 + t * 16 + m) * DIM_P;
        afrag[t][0] = *reinterpret_cast<const bf16x8*>(wrow + kb);
        afrag[t][1] = *reinterpret_cast<const bf16x8*>(wrow + 32 + kb);
        int cc = c0 + t * 16 + quad * 4;
        bias[t] = (cc < DIM_OUT) ? *reinterpret_cast<const float4*>(bout + cc)
                                 : make_float4(0.f, 0.f, 0.f, 0.f);
    }

    const int NT = N_NODES / 16;  // 3125 row tiles
    for (int rt = blockIdx.x; rt < NT; rt += gridDim.x) {
        const int row = rt * 16 + m;
        const unsigned short* arow = ABF + (size_t)row * DIM_P;
        bf16x8 bfrag0 = *reinterpret_cast<const bf16x8*>(arow + kb);
        bf16x8 bfrag1 = *reinterpret_cast<const bf16x8*>(arow + 32 + kb);
        float* orow = out + (size_t)row * DIM_OUT;
#pragma unroll
        for (int t = 0; t < 4; ++t) {
            floatx4 acc = {0.f, 0.f, 0.f, 0.f};
            acc = __builtin_amdgcn_mfma_f32_16x16x32_bf16(afrag[t][0], bfrag0, acc, 0, 0, 0);
            acc = __builtin_amdgcn_mfma_f32_16x16x32_bf16(afrag[t][1], bfrag1, acc, 0, 0, 0);
            int cc = c0 + t * 16 + quad * 4;
            if (cc < DIM_OUT) {
                float4 o = make_float4(acc[0] + bias[t].x, acc[1] + bias[t].y,
                                       acc[2] + bias[t].z, acc[3] + bias[t].w);
                *reinterpret_cast<float4*>(orow + cc) = o;
            }
        }
    }
}

// ---------------- launch ----------------
extern "C" void kernel_launch(void* const* d_in, const int* in_sizes, int n_in,
                              void* d_out, int out_size, void* d_ws, size_t ws_size,
                              hipStream_t stream) {
    const float* x    = (const float*)d_in[0];
    const int*   ei   = (const int*)  d_in[1];
    const float* W1   = (const float*)d_in[2];
    const float* g1   = (const float*)d_in[4];
    const float* be1  = (const float*)d_in[5];
    const float* W2   = (const float*)d_in[6];
    const float* g2   = (const float*)d_in[8];
    const float* be2  = (const float*)d_in[9];
    const float* att  = (const float*)d_in[10];
    const float* W3   = (const float*)d_in[11];
    const float* g3   = (const float*)d_in[13];
    const float* be3  = (const float*)d_in[14];
    const float* Wout = (const float*)d_in[15];
    const float* bout = (const float*)d_in[16];
    float* out = (float*)d_out;

    char* base = (char*)d_ws;
    size_t off = 0;
    auto alloc = [&](size_t bytes) -> void* {
        void* r = base + off;
        off += (bytes + 255) & ~(size_t)255;
        return r;
    };
    float*  f0      = (float*) alloc((size_t)N_NODES * DIM_H * 4); // z1
    float*  f1      = (float*) alloc((size_t)N_NODES * DIM_H * 4); // z2
    float*  yb      = (float*) alloc((size_t)N_NODES * DIM_P * 4); // y = act@W3, ping
    float*  tb      = (float*) alloc((size_t)N_NODES * DIM_P * 4); // pong
    float*  oa      = (float*) alloc((size_t)N_NODES * DIM_P * 4); // weighted accumulator
    double* st      = (double*)alloc(640 * 8);
    float*  scsh    = (float*) alloc(768 * 4);
    float*  wts     = (float*) alloc(16 * 4);
    int*    row_ptr = (int*)   alloc((size_t)(N_NODES + 1) * 4);
    int*    deg     = (int*)   alloc((size_t)N_NODES * 4);   // degree -> cursor
    int*    col     = (int*)   alloc((size_t)N_EDGES * 4);
    int*    bsums   = (int*)   alloc(64 * 4);
    unsigned short* WT  = (unsigned short*)alloc((size_t)OUT_PAD * DIM_P * 2);
    unsigned short* ABF = (unsigned short*)alloc((size_t)N_NODES * DIM_P * 2);

    const int* src = ei;
    const int* dst = ei + N_EDGES;
    double* st1 = st;   double* st2 = st + 256; double* st3 = st + 512;
    float*  sc1 = scsh; float*  sc2 = scsh + 256; float* sc3 = scsh + 512;

    hipMemsetAsync(st, 0, 640 * 8, stream);
    hipMemsetAsync(deg, 0, (size_t)N_NODES * 4, stream);

    softmax11<<<1, 64, 0, stream>>>(att, wts);
    prep_wout<<<ceil_div(OUT_PAD * DIM_P, 256), 256, 0, stream>>>(Wout, WT);

    // CSR by destination (fast 3-stage scan)
    count_deg<<<ceil_div(N_EDGES, 256), 256, 0, stream>>>(dst, deg, N_EDGES);
    const int NB = ceil_div(N_NODES, 1024);
    scan_local<<<NB, 1024, 0, stream>>>(deg, row_ptr, bsums, N_NODES);
    scan_bsums<<<1, 64, 0, stream>>>(bsums, NB);
    scan_finish<<<ceil_div(N_NODES, 256), 256, 0, stream>>>(row_ptr, deg, bsums, N_NODES);
    fill_csr<<<ceil_div(N_EDGES, 256), 256, 0, stream>>>(src, dst, deg, col, N_EDGES);

    const int RB = ceil_div(N_NODES, 64);

    // layer 1: z1 = x@W1 ; stats (b1 cancels in BN)
    gemm_fused<128, 128><<<dim3(RB, 1), 256, 0, stream>>>(
        x, nullptr, nullptr, nullptr, W1, nullptr, f0, nullptr, nullptr, N_NODES, DIM_H);
    colstats<128><<<256, 256, 0, stream>>>(f0, st1, N_NODES);
    bn_finalize<<<1, 128, 0, stream>>>(st1, g1, be1, sc1, 128, N_NODES);

    // layer 2: z2 = relu(bn1(z1)) @ W2  (bn1+relu fused into A-staging)
    gemm_fused<128, 128><<<dim3(RB, 1), 256, 0, stream>>>(
        f0, sc1, nullptr, nullptr, W2, nullptr, f1, nullptr, nullptr, N_NODES, DIM_H);
    colstats<128><<<256, 256, 0, stream>>>(f1, st2, N_NODES);
    bn_finalize<<<1, 128, 0, stream>>>(st2, g2, be2, sc2, 128, N_NODES);

    // layer 3 input: h2 = relu(bn2(z2)) + relu(bn1(z1)); y = h2@W3; oa = w0*y
    gemm_fused<128, 64><<<dim3(RB, 1), 256, 0, stream>>>(
        f1, sc2, f0, sc1, W3, nullptr, yb, oa, wts, N_NODES, DIM_P);

    // all 10 hops in one persistent cooperative kernel (grid.sync between hops)
    {
        float* b0 = yb; float* b1 = tb; float* oap = oa;
        int*   rp = row_ptr; int* cl = col; float* wp = wts;
        int    nn = N_NODES;
        void* args[] = { &b0, &b1, &oap, &rp, &cl, &wp, &nn };
        hipLaunchCooperativeKernel(propagate_all, dim3(1024), dim3(256),
                                   args, 0, stream);
    }

    // layer 3 BN stats (b3 cancels); then bn3+relu+bf16 applied ONCE
    colstats<64><<<256, 256, 0, stream>>>(oa, st3, N_NODES);
    bn_finalize<<<1, 64, 0, stream>>>(st3, g3, be3, sc3, 64, N_NODES);
    bn3_relu_bf16<<<ceil_div(N_NODES * DIM_P / 8, 256), 256, 0, stream>>>(oa, sc3, ABF);

    // output: out = ABF @ Wout + bout   (bf16 MFMA, column-persistent waves)
    out_gemm_mfma<<<dim3(512, 4), 256, 0, stream>>>(ABF, WT, bout, out);
}

// Round 6
// 1506.088 us; speedup vs baseline: 2.1533x; 2.1533x over previous
//
#include <hip/hip_runtime.h>
#include <cstdint>
#include <cstddef>

#define N_NODES 50000
#define N_EDGES 800000
#define DIM_H   128
#define DIM_P   64     // propagation width after commuting W3
#define DIM_OUT 1000
#define OUT_PAD 1024   // padded col count for MFMA tiles
#define KHOPS   10
#define BN_EPS  1e-5f

static inline int ceil_div(int a, int b) { return (a + b - 1) / b; }

typedef short  bf16x8  __attribute__((ext_vector_type(8)));
typedef float  floatx4 __attribute__((ext_vector_type(4)));

__device__ __forceinline__ unsigned short f2bf_rne(float v) {
    unsigned int u = __float_as_uint(v);
    return (unsigned short)((u + 0x7fffu + ((u >> 16) & 1u)) >> 16);
}

// ---------------- softmax over att[11] ----------------
__global__ void softmax11(const float* __restrict__ att, float* __restrict__ w) {
    if (threadIdx.x == 0) {
        float mx = att[0];
        for (int i = 1; i < KHOPS + 1; ++i) mx = fmaxf(mx, att[i]);
        float e[KHOPS + 1];
        float s = 0.f;
        for (int i = 0; i < KHOPS + 1; ++i) { e[i] = expf(att[i] - mx); s += e[i]; }
        for (int i = 0; i < KHOPS + 1; ++i) w[i] = e[i] / s;
    }
}

// ---------------- CSR build ----------------
__global__ void count_deg(const int* __restrict__ dst, int* __restrict__ deg, int ne) {
    int i = blockIdx.x * blockDim.x + threadIdx.x;
    if (i < ne) atomicAdd(&deg[dst[i]], 1);
}

// local inclusive scan per 1024-block (shuffle-based, 3 barriers)
__global__ __launch_bounds__(1024) void scan_local(const int* __restrict__ deg,
                                                   int* __restrict__ row_ptr,
                                                   int* __restrict__ bsums, int n) {
    __shared__ int wsum[16];
    const int i = blockIdx.x * 1024 + threadIdx.x;
    const int lane = threadIdx.x & 63, w = threadIdx.x >> 6;
    int v = (i < n) ? deg[i] : 0;
    int s = v;
#pragma unroll
    for (int d = 1; d < 64; d <<= 1) {
        int t = __shfl_up(s, d, 64);
        if (lane >= d) s += t;
    }
    if (lane == 63) wsum[w] = s;
    __syncthreads();
    if (w == 0) {
        int x = (lane < 16) ? wsum[lane] : 0;
#pragma unroll
        for (int d = 1; d < 16; d <<= 1) {
            int t = __shfl_up(x, d, 64);
            if (lane >= d) x += t;
        }
        if (lane < 16) wsum[lane] = x;
    }
    __syncthreads();
    int incl = s + ((w > 0) ? wsum[w - 1] : 0);
    if (i < n) row_ptr[i + 1] = incl;
    if (threadIdx.x == 1023) bsums[blockIdx.x] = incl;
}

// exclusive scan of block sums (nb <= 64), single wave
__global__ void scan_bsums(int* __restrict__ bsums, int nb) {
    int lane = threadIdx.x;
    int v = (lane < nb) ? bsums[lane] : 0;
    int s = v;
#pragma unroll
    for (int d = 1; d < 64; d <<= 1) {
        int t = __shfl_up(s, d, 64);
        if (lane >= d) s += t;
    }
    if (lane < nb) bsums[lane] = s - v;
}

// add block offsets; also derive fill-cursor (exclusive start) in-place in deg
__global__ void scan_finish(int* __restrict__ row_ptr, int* __restrict__ deg,
                            const int* __restrict__ bsums, int n) {
    int i = blockIdx.x * blockDim.x + threadIdx.x;
    if (i < n) {
        int incl = row_ptr[i + 1] + bsums[i >> 10];
        row_ptr[i + 1] = incl;
        deg[i] = incl - deg[i];   // cursor = exclusive prefix
    }
    if (i == 0) row_ptr[0] = 0;
}

__global__ void fill_csr(const int* __restrict__ src, const int* __restrict__ dst,
                         int* __restrict__ cursor, int* __restrict__ col, int ne) {
    int i = blockIdx.x * blockDim.x + threadIdx.x;
    if (i < ne) {
        int d = dst[i];
        int pos = atomicAdd(&cursor[d], 1);
        col[pos] = src[i];
    }
}

// ---------------- fused GEMM: C[n,M] = act(A) @ W (+bias) -------------------
// act(A) row = relu(A*scA+shA)  [if scA]  +  relu(A2*scA2+shA2)  [if A2]
// optional second output C2 = w0p[0] * C  (fused scale_init)
// BLK: store C/C2 in slice-major blocked layout [M/8][n][8] for XCD-local hops
template<int KD, int CPB, bool BLK>
__global__ __launch_bounds__(256) void gemm_fused(
    const float* __restrict__ A,  const float* __restrict__ scA,
    const float* __restrict__ A2, const float* __restrict__ scA2,
    const float* __restrict__ W,  const float* __restrict__ bias,
    float* __restrict__ C, float* __restrict__ C2, const float* __restrict__ w0p,
    int n, int M) {
    constexpr int CG  = CPB / 4;     // col groups per block
    constexpr int RG  = 256 / CG;    // row groups
    constexpr int RPT = 64 / RG;     // rows per thread
    __shared__ float As[64][KD + 4];

    const int tid  = threadIdx.x;
    const int cg   = tid % CG;
    const int rg   = tid / CG;
    const int row0 = blockIdx.x * 64;
    const int col0 = blockIdx.y * CPB + cg * 4;

    constexpr int VECS = 64 * KD / 4;
    for (int i = tid; i < VECS; i += 256) {
        int r  = i / (KD / 4);
        int k4 = (i % (KD / 4)) * 4;
        float4 v = make_float4(0.f, 0.f, 0.f, 0.f);
        int row = row0 + r;
        if (row < n) {
            v = *reinterpret_cast<const float4*>(A + (size_t)row * KD + k4);
            if (scA) {
                float4 sc = *reinterpret_cast<const float4*>(scA + k4);
                float4 sh = *reinterpret_cast<const float4*>(scA + KD + k4);
                v.x = fmaxf(v.x * sc.x + sh.x, 0.f);
                v.y = fmaxf(v.y * sc.y + sh.y, 0.f);
                v.z = fmaxf(v.z * sc.z + sh.z, 0.f);
                v.w = fmaxf(v.w * sc.w + sh.w, 0.f);
            }
            if (A2) {
                float4 u  = *reinterpret_cast<const float4*>(A2 + (size_t)row * KD + k4);
                float4 sc = *reinterpret_cast<const float4*>(scA2 + k4);
                float4 sh = *reinterpret_cast<const float4*>(scA2 + KD + k4);
                v.x += fmaxf(u.x * sc.x + sh.x, 0.f);
                v.y += fmaxf(u.y * sc.y + sh.y, 0.f);
                v.z += fmaxf(u.z * sc.z + sh.z, 0.f);
                v.w += fmaxf(u.w * sc.w + sh.w, 0.f);
            }
        }
        *reinterpret_cast<float4*>(&As[r][k4]) = v;
    }
    __syncthreads();

    if (col0 >= M) return;

    float acc[RPT][4];
#pragma unroll
    for (int r = 0; r < RPT; ++r)
#pragma unroll
        for (int c = 0; c < 4; ++c) acc[r][c] = 0.f;

    for (int k4 = 0; k4 < KD; k4 += 4) {
        float4 w0 = *reinterpret_cast<const float4*>(W + (size_t)(k4 + 0) * M + col0);
        float4 w1 = *reinterpret_cast<const float4*>(W + (size_t)(k4 + 1) * M + col0);
        float4 w2 = *reinterpret_cast<const float4*>(W + (size_t)(k4 + 2) * M + col0);
        float4 w3 = *reinterpret_cast<const float4*>(W + (size_t)(k4 + 3) * M + col0);
#pragma unroll
        for (int r = 0; r < RPT; ++r) {
            float4 a = *reinterpret_cast<const float4*>(&As[rg * RPT + r][k4]);
            acc[r][0] += a.x * w0.x + a.y * w1.x + a.z * w2.x + a.w * w3.x;
            acc[r][1] += a.x * w0.y + a.y * w1.y + a.z * w2.y + a.w * w3.y;
            acc[r][2] += a.x * w0.z + a.y * w1.z + a.z * w2.z + a.w * w3.z;
            acc[r][3] += a.x * w0.w + a.y * w1.w + a.z * w2.w + a.w * w3.w;
        }
    }

    float4 b = make_float4(0.f, 0.f, 0.f, 0.f);
    if (bias) b = *reinterpret_cast<const float4*>(bias + col0);
    const float w0s = C2 ? w0p[0] : 0.f;
#pragma unroll
    for (int r = 0; r < RPT; ++r) {
        int row = row0 + rg * RPT + r;
        if (row < n) {
            float4 o = make_float4(acc[r][0] + b.x, acc[r][1] + b.y,
                                   acc[r][2] + b.z, acc[r][3] + b.w);
            size_t oaddr;
            if (BLK) {
                oaddr = (size_t)(col0 >> 3) * ((size_t)n * 8) + (size_t)row * 8 + (col0 & 7);
            } else {
                oaddr = (size_t)row * M + col0;
            }
            *reinterpret_cast<float4*>(C + oaddr) = o;
            if (C2) {
                float4 q = make_float4(w0s * o.x, w0s * o.y, w0s * o.z, w0s * o.w);
                *reinterpret_cast<float4*>(C2 + oaddr) = q;
            }
        }
    }
}

// ---------------- BN column stats (sum, sumsq) in double ----------------
template<int M>
__global__ __launch_bounds__(256) void colstats(const float* __restrict__ Z,
                                                double* __restrict__ st, int n) {
    constexpr int RG = 256 / M;
    const int tid = threadIdx.x;
    const int c = tid % M, rg = tid / M;
    double s = 0.0, ss = 0.0;
    for (int row = blockIdx.x * RG + rg; row < n; row += gridDim.x * RG) {
        float v = Z[(size_t)row * M + c];
        s += v;
        ss += (double)v * (double)v;
    }
    __shared__ double sh[2][256];
    sh[0][tid] = s;
    sh[1][tid] = ss;
    __syncthreads();
    if (rg == 0) {
#pragma unroll
        for (int g = 1; g < RG; ++g) { s += sh[0][c + g * M]; ss += sh[1][c + g * M]; }
        atomicAdd(&st[c], s);
        atomicAdd(&st[M + c], ss);
    }
}

// colstats over blocked [8][n][8] layout (M=64)
__global__ __launch_bounds__(256) void colstats64_blk(const float* __restrict__ Z,
                                                      double* __restrict__ st, int n) {
    const int tid = threadIdx.x;
    const int c = tid & 63, rg = tid >> 6;          // RG = 4
    const int blk = c >> 3, j = c & 7;
    const float* base = Z + (size_t)blk * (size_t)n * 8 + j;
    double s = 0.0, ss = 0.0;
    for (int row = blockIdx.x * 4 + rg; row < n; row += gridDim.x * 4) {
        float v = base[(size_t)row * 8];
        s += v;
        ss += (double)v * (double)v;
    }
    __shared__ double sh[2][256];
    sh[0][tid] = s;
    sh[1][tid] = ss;
    __syncthreads();
    if (rg == 0) {
#pragma unroll
        for (int g2 = 1; g2 < 4; ++g2) { s += sh[0][c + g2 * 64]; ss += sh[1][c + g2 * 64]; }
        atomicAdd(&st[c], s);
        atomicAdd(&st[64 + c], ss);
    }
}

__global__ void bn_finalize(const double* __restrict__ st, const float* __restrict__ g,
                            const float* __restrict__ be, float* __restrict__ scsh,
                            int M, int n) {
    int c = threadIdx.x + blockIdx.x * blockDim.x;
    if (c < M) {
        double m = st[c] / n;
        double v = st[M + c] / n - m * m;
        float scale = g[c] * rsqrtf((float)v + BN_EPS);
        scsh[c]     = scale;
        scsh[M + c] = be[c] - (float)m * scale;
    }
}

// ---------------- one propagation hop, slice-major blocked state -------------
// State layout [8][n][8]: slice s is a contiguous 1.6 MB table -> fits per-XCD
// L2. slice = blockIdx & 7 pairs with the round-robin block->XCD mapping so a
// slice's ~16x/row reuse stays inside one XCD's L2. One wave per (node,slice):
// lane pairs (g=lane>>1 neighbor slot 0..31, l=lane&1 float4 half) -> up to 32
// neighbors per gather instruction, exec-mask predicated (no wasted fetches).
__global__ __launch_bounds__(256) void propagate_blk(
    const float* __restrict__ cur, float* __restrict__ nxt, float* __restrict__ oacc,
    const int* __restrict__ row_ptr, const int* __restrict__ col,
    const float* __restrict__ wts, int hop, int n) {
    const int slice   = blockIdx.x & 7;
    const int chunk   = blockIdx.x >> 3;
    const int nchunks = gridDim.x >> 3;
    const int wv   = threadIdx.x >> 6;
    const int lane = threadIdx.x & 63;
    const int g = lane >> 1;
    const int l = lane & 1;
    const float w = wts[hop];
    const size_t sbase = (size_t)slice * (size_t)n * 8;

    for (int node = chunk * 4 + wv; node < n; node += nchunks * 4) {
        const int beg = row_ptr[node], end = row_ptr[node + 1];
        float ax = 0.f, ay = 0.f, az = 0.f, aw = 0.f;
        for (int e = beg; e + g < end; e += 32) {
            int s = col[e + g];
            float4 v = *reinterpret_cast<const float4*>(cur + sbase + (size_t)s * 8 + l * 4);
            ax += v.x; ay += v.y; az += v.z; aw += v.w;
        }
#pragma unroll
        for (int off = 2; off < 64; off <<= 1) {
            ax += __shfl_xor(ax, off, 64);
            ay += __shfl_xor(ay, off, 64);
            az += __shfl_xor(az, off, 64);
            aw += __shfl_xor(aw, off, 64);
        }
        if (g == 0) {
            size_t o = sbase + (size_t)node * 8 + l * 4;
            if (nxt) {
                float4 s4 = make_float4(ax, ay, az, aw);
                *reinterpret_cast<float4*>(nxt + o) = s4;
            }
            float4 t = *reinterpret_cast<const float4*>(oacc + o);
            t.x = fmaf(w, ax, t.x); t.y = fmaf(w, ay, t.y);
            t.z = fmaf(w, az, t.z); t.w = fmaf(w, aw, t.w);
            *reinterpret_cast<float4*>(oacc + o) = t;
        }
    }
}

// ---------------- Wout transpose + bf16 convert: WT[c][k] = bf16(W[k][c]) ----
// padded to OUT_PAD rows; pad rows are zero so MFMA tiles past col 999 are inert
__global__ void prep_wout(const float* __restrict__ W, unsigned short* __restrict__ WT) {
    int idx = blockIdx.x * blockDim.x + threadIdx.x;  // idx = c*64 + k
    if (idx < OUT_PAD * DIM_P) {
        int c = idx >> 6, k = idx & 63;
        WT[idx] = (c < DIM_OUT) ? f2bf_rne(W[(size_t)k * DIM_OUT + c]) : (unsigned short)0;
    }
}

// ------- bn3 + relu + bf16 convert from blocked [8][n][8] -> ABF[row][64] ----
__global__ void bn3_relu_bf16_blk(const float* __restrict__ Z, const float* __restrict__ scsh,
                                  unsigned short* __restrict__ O, int n) {
    int i = blockIdx.x * blockDim.x + threadIdx.x;   // i < n*8
    if (i >= n * 8) return;
    int row = i >> 3, blk = i & 7;
    const float* zp = Z + (size_t)blk * (size_t)n * 8 + (size_t)row * 8;
    float4 z0 = *reinterpret_cast<const float4*>(zp);
    float4 z1 = *reinterpret_cast<const float4*>(zp + 4);
    int c = blk * 8;
    float4 s0 = *reinterpret_cast<const float4*>(scsh + c);
    float4 s1 = *reinterpret_cast<const float4*>(scsh + c + 4);
    float4 h0 = *reinterpret_cast<const float4*>(scsh + DIM_P + c);
    float4 h1 = *reinterpret_cast<const float4*>(scsh + DIM_P + c + 4);
    bf16x8 o;
    o[0] = (short)f2bf_rne(fmaxf(z0.x * s0.x + h0.x, 0.f));
    o[1] = (short)f2bf_rne(fmaxf(z0.y * s0.y + h0.y, 0.f));
    o[2] = (short)f2bf_rne(fmaxf(z0.z * s0.z + h0.z, 0.f));
    o[3] = (short)f2bf_rne(fmaxf(z0.w * s0.w + h0.w, 0.f));
    o[4] = (short)f2bf_rne(fmaxf(z1.x * s1.x + h1.x, 0.f));
    o[5] = (short)f2bf_rne(fmaxf(z1.y * s1.y + h1.y, 0.f));
    o[6] = (short)f2bf_rne(fmaxf(z1.z * s1.z + h1.z, 0.f));
    o[7] = (short)f2bf_rne(fmaxf(z1.w * s1.w + h1.w, 0.f));
    *reinterpret_cast<bf16x8*>(O + (size_t)row * 64 + blk * 8) = o;
}

// ---------------- final GEMM via MFMA: out = ABF @ Wout + bout ----------------
// A-operand = Wout columns (register-resident across row loop), B = node rows.
// Each lane stores float4 of 4 consecutive output columns.
__global__ __launch_bounds__(256, 4) void out_gemm_mfma(
    const unsigned short* __restrict__ ABF, const unsigned short* __restrict__ WT,
    const float* __restrict__ bout, float* __restrict__ out) {
    const int wave = threadIdx.x >> 6;
    const int lane = threadIdx.x & 63;
    const int m    = lane & 15;       // A: out-col within tile; B/D: out-row
    const int quad = lane >> 4;
    const int kb   = quad * 8;
    const int c0   = blockIdx.y * 256 + wave * 64;

    bf16x8 afrag[4][2];
    float4 bias[4];
#pragma unroll
    for (int t = 0; t < 4; ++t) {
        const unsigned short* wrow = WT + (size_t)(c0 + t * 16 + m) * DIM_P;
        afrag[t][0] = *reinterpret_cast<const bf16x8*>(wrow + kb);
        afrag[t][1] = *reinterpret_cast<const bf16x8*>(wrow + 32 + kb);
        int cc = c0 + t * 16 + quad * 4;
        bias[t] = (cc < DIM_OUT) ? *reinterpret_cast<const float4*>(bout + cc)
                                 : make_float4(0.f, 0.f, 0.f, 0.f);
    }

    const int NT = N_NODES / 16;  // 3125 row tiles
    for (int rt = blockIdx.x; rt < NT; rt += gridDim.x) {
        const int row = rt * 16 + m;
        const unsigned short* arow = ABF + (size_t)row * DIM_P;
        bf16x8 bfrag0 = *reinterpret_cast<const bf16x8*>(arow + kb);
        bf16x8 bfrag1 = *reinterpret_cast<const bf16x8*>(arow + 32 + kb);
        float* orow = out + (size_t)row * DIM_OUT;
#pragma unroll
        for (int t = 0; t < 4; ++t) {
            floatx4 acc = {0.f, 0.f, 0.f, 0.f};
            acc = __builtin_amdgcn_mfma_f32_16x16x32_bf16(afrag[t][0], bfrag0, acc, 0, 0, 0);
            acc = __builtin_amdgcn_mfma_f32_16x16x32_bf16(afrag[t][1], bfrag1, acc, 0, 0, 0);
            int cc = c0 + t * 16 + quad * 4;
            if (cc < DIM_OUT) {
                float4 o = make_float4(acc[0] + bias[t].x, acc[1] + bias[t].y,
                                       acc[2] + bias[t].z, acc[3] + bias[t].w);
                *reinterpret_cast<float4*>(orow + cc) = o;
            }
        }
    }
}

// ---------------- launch ----------------
extern "C" void kernel_launch(void* const* d_in, const int* in_sizes, int n_in,
                              void* d_out, int out_size, void* d_ws, size_t ws_size,
                              hipStream_t stream) {
    const float* x    = (const float*)d_in[0];
    const int*   ei   = (const int*)  d_in[1];
    const float* W1   = (const float*)d_in[2];
    const float* g1   = (const float*)d_in[4];
    const float* be1  = (const float*)d_in[5];
    const float* W2   = (const float*)d_in[6];
    const float* g2   = (const float*)d_in[8];
    const float* be2  = (const float*)d_in[9];
    const float* att  = (const float*)d_in[10];
    const float* W3   = (const float*)d_in[11];
    const float* g3   = (const float*)d_in[13];
    const float* be3  = (const float*)d_in[14];
    const float* Wout = (const float*)d_in[15];
    const float* bout = (const float*)d_in[16];
    float* out = (float*)d_out;

    char* base = (char*)d_ws;
    size_t off = 0;
    auto alloc = [&](size_t bytes) -> void* {
        void* r = base + off;
        off += (bytes + 255) & ~(size_t)255;
        return r;
    };
    float*  f0      = (float*) alloc((size_t)N_NODES * DIM_H * 4); // z1
    float*  f1      = (float*) alloc((size_t)N_NODES * DIM_H * 4); // z2
    float*  yb      = (float*) alloc((size_t)N_NODES * DIM_P * 4); // y blocked, ping
    float*  tb      = (float*) alloc((size_t)N_NODES * DIM_P * 4); // blocked, pong
    float*  oa      = (float*) alloc((size_t)N_NODES * DIM_P * 4); // blocked accumulator
    double* st      = (double*)alloc(640 * 8);
    float*  scsh    = (float*) alloc(768 * 4);
    float*  wts     = (float*) alloc(16 * 4);
    int*    row_ptr = (int*)   alloc((size_t)(N_NODES + 1) * 4);
    int*    deg     = (int*)   alloc((size_t)N_NODES * 4);   // degree -> cursor
    int*    col     = (int*)   alloc((size_t)N_EDGES * 4);
    int*    bsums   = (int*)   alloc(64 * 4);
    unsigned short* WT  = (unsigned short*)alloc((size_t)OUT_PAD * DIM_P * 2);
    unsigned short* ABF = (unsigned short*)alloc((size_t)N_NODES * DIM_P * 2);

    const int* src = ei;
    const int* dst = ei + N_EDGES;
    double* st1 = st;   double* st2 = st + 256; double* st3 = st + 512;
    float*  sc1 = scsh; float*  sc2 = scsh + 256; float* sc3 = scsh + 512;

    hipMemsetAsync(st, 0, 640 * 8, stream);
    hipMemsetAsync(deg, 0, (size_t)N_NODES * 4, stream);

    softmax11<<<1, 64, 0, stream>>>(att, wts);
    prep_wout<<<ceil_div(OUT_PAD * DIM_P, 256), 256, 0, stream>>>(Wout, WT);

    // CSR by destination (fast 3-stage scan)
    count_deg<<<ceil_div(N_EDGES, 256), 256, 0, stream>>>(dst, deg, N_EDGES);
    const int NB = ceil_div(N_NODES, 1024);
    scan_local<<<NB, 1024, 0, stream>>>(deg, row_ptr, bsums, N_NODES);
    scan_bsums<<<1, 64, 0, stream>>>(bsums, NB);
    scan_finish<<<ceil_div(N_NODES, 256), 256, 0, stream>>>(row_ptr, deg, bsums, N_NODES);
    fill_csr<<<ceil_div(N_EDGES, 256), 256, 0, stream>>>(src, dst, deg, col, N_EDGES);

    const int RB = ceil_div(N_NODES, 64);

    // layer 1: z1 = x@W1 (b1 cancels in BN)
    gemm_fused<128, 128, false><<<dim3(RB, 1), 256, 0, stream>>>(
        x, nullptr, nullptr, nullptr, W1, nullptr, f0, nullptr, nullptr, N_NODES, DIM_H);
    colstats<128><<<256, 256, 0, stream>>>(f0, st1, N_NODES);
    bn_finalize<<<1, 128, 0, stream>>>(st1, g1, be1, sc1, 128, N_NODES);

    // layer 2: z2 = relu(bn1(z1)) @ W2  (bn1+relu fused into A-staging)
    gemm_fused<128, 128, false><<<dim3(RB, 1), 256, 0, stream>>>(
        f0, sc1, nullptr, nullptr, W2, nullptr, f1, nullptr, nullptr, N_NODES, DIM_H);
    colstats<128><<<256, 256, 0, stream>>>(f1, st2, N_NODES);
    bn_finalize<<<1, 128, 0, stream>>>(st2, g2, be2, sc2, 128, N_NODES);

    // layer 3 input: h2 = relu(bn2(z2)) + relu(bn1(z1)); y = h2@W3 (BLOCKED out);
    // oa = w0*y fused
    gemm_fused<128, 64, true><<<dim3(RB, 1), 256, 0, stream>>>(
        f1, sc2, f0, sc1, W3, nullptr, yb, oa, wts, N_NODES, DIM_P);

    // 10 hops, slice-major blocked state, launch per hop (L2 stays warm)
    {
        const int PBLK = 4096;                 // node chunks per slice
        float* cur = yb;
        float* nxt = tb;
        for (int hop = 1; hop <= KHOPS; ++hop) {
            propagate_blk<<<dim3(8 * PBLK), 256, 0, stream>>>(
                cur, (hop == KHOPS) ? nullptr : nxt, oa, row_ptr, col, wts, hop, N_NODES);
            float* t = cur; cur = nxt; nxt = t;
        }
    }

    // layer 3 BN stats (b3 cancels); then bn3+relu+bf16 applied ONCE (blocked in)
    colstats64_blk<<<256, 256, 0, stream>>>(oa, st3, N_NODES);
    bn_finalize<<<1, 64, 0, stream>>>(st3, g3, be3, sc3, 64, N_NODES);
    bn3_relu_bf16_blk<<<ceil_div(N_NODES * 8, 256), 256, 0, stream>>>(oa, sc3, ABF, N_NODES);

    // output: out = ABF @ Wout + bout   (bf16 MFMA, column-persistent waves)
    out_gemm_mfma<<<dim3(512, 4), 256, 0, stream>>>(ABF, WT, bout, out);
}

// Round 8
// 799.204 us; speedup vs baseline: 4.0578x; 1.8845x over previous
//
#include <hip/hip_runtime.h>
#include <cstdint>
#include <cstddef>

#define N_NODES 50000
#define N_EDGES 800000
#define DIM_H   128
#define DIM_P   64     // propagation width after commuting W3
#define DIM_OUT 1000
#define OUT_PAD 1024   // padded col count for MFMA tiles
#define KHOPS   10
#define BN_EPS  1e-5f

static inline int ceil_div(int a, int b) { return (a + b - 1) / b; }

typedef short  bf16x8  __attribute__((ext_vector_type(8)));
typedef float  floatx4 __attribute__((ext_vector_type(4)));

__device__ __forceinline__ unsigned short f2bf_rne(float v) {
    unsigned int u = __float_as_uint(v);
    return (unsigned short)((u + 0x7fffu + ((u >> 16) & 1u)) >> 16);
}
__device__ __forceinline__ float bf2f(unsigned short u) {
    return __uint_as_float((unsigned int)u << 16);
}

// ---------------- softmax over att[11] ----------------
__global__ void softmax11(const float* __restrict__ att, float* __restrict__ w) {
    if (threadIdx.x == 0) {
        float mx = att[0];
        for (int i = 1; i < KHOPS + 1; ++i) mx = fmaxf(mx, att[i]);
        float e[KHOPS + 1];
        float s = 0.f;
        for (int i = 0; i < KHOPS + 1; ++i) { e[i] = expf(att[i] - mx); s += e[i]; }
        for (int i = 0; i < KHOPS + 1; ++i) w[i] = e[i] / s;
    }
}

// ---------------- CSR build ----------------
__global__ void count_deg(const int* __restrict__ dst, int* __restrict__ deg, int ne) {
    int i = blockIdx.x * blockDim.x + threadIdx.x;
    if (i < ne) atomicAdd(&deg[dst[i]], 1);
}

// local inclusive scan per 1024-block (shuffle-based, 3 barriers)
__global__ __launch_bounds__(1024) void scan_local(const int* __restrict__ deg,
                                                   int* __restrict__ row_ptr,
                                                   int* __restrict__ bsums, int n) {
    __shared__ int wsum[16];
    const int i = blockIdx.x * 1024 + threadIdx.x;
    const int lane = threadIdx.x & 63, w = threadIdx.x >> 6;
    int v = (i < n) ? deg[i] : 0;
    int s = v;
#pragma unroll
    for (int d = 1; d < 64; d <<= 1) {
        int t = __shfl_up(s, d, 64);
        if (lane >= d) s += t;
    }
    if (lane == 63) wsum[w] = s;
    __syncthreads();
    if (w == 0) {
        int x = (lane < 16) ? wsum[lane] : 0;
#pragma unroll
        for (int d = 1; d < 16; d <<= 1) {
            int t = __shfl_up(x, d, 64);
            if (lane >= d) x += t;
        }
        if (lane < 16) wsum[lane] = x;
    }
    __syncthreads();
    int incl = s + ((w > 0) ? wsum[w - 1] : 0);
    if (i < n) row_ptr[i + 1] = incl;
    if (threadIdx.x == 1023) bsums[blockIdx.x] = incl;
}

// exclusive scan of block sums (nb <= 64), single wave
__global__ void scan_bsums(int* __restrict__ bsums, int nb) {
    int lane = threadIdx.x;
    int v = (lane < nb) ? bsums[lane] : 0;
    int s = v;
#pragma unroll
    for (int d = 1; d < 64; d <<= 1) {
        int t = __shfl_up(s, d, 64);
        if (lane >= d) s += t;
    }
    if (lane < nb) bsums[lane] = s - v;
}

// add block offsets; also derive fill-cursor (exclusive start) in-place in deg
__global__ void scan_finish(int* __restrict__ row_ptr, int* __restrict__ deg,
                            const int* __restrict__ bsums, int n) {
    int i = blockIdx.x * blockDim.x + threadIdx.x;
    if (i < n) {
        int incl = row_ptr[i + 1] + bsums[i >> 10];
        row_ptr[i + 1] = incl;
        deg[i] = incl - deg[i];   // cursor = exclusive prefix
    }
    if (i == 0) row_ptr[0] = 0;
}

__global__ void fill_csr(const int* __restrict__ src, const int* __restrict__ dst,
                         int* __restrict__ cursor, int* __restrict__ col, int ne) {
    int i = blockIdx.x * blockDim.x + threadIdx.x;
    if (i < ne) {
        int d = dst[i];
        int pos = atomicAdd(&cursor[d], 1);
        col[pos] = src[i];
    }
}

// ---------------- fused GEMM: C[n,M] = act(A) @ W (+bias) -------------------
// act(A) row = relu(A*scA+shA)  [if scA]  +  relu(A2*scA2+shA2)  [if A2]
// optional second output C2 = w0p[0] * C (fp32, fused scale_init)
// OBF: write C as bf16 (the propagation hop state); C2 stays fp32.
template<int KD, int CPB, bool OBF>
__global__ __launch_bounds__(256) void gemm_fused(
    const float* __restrict__ A,  const float* __restrict__ scA,
    const float* __restrict__ A2, const float* __restrict__ scA2,
    const float* __restrict__ W,  const float* __restrict__ bias,
    float* __restrict__ C, float* __restrict__ C2, const float* __restrict__ w0p,
    int n, int M) {
    constexpr int CG  = CPB / 4;     // col groups per block
    constexpr int RG  = 256 / CG;    // row groups
    constexpr int RPT = 64 / RG;     // rows per thread
    __shared__ float As[64][KD + 4];

    const int tid  = threadIdx.x;
    const int cg   = tid % CG;
    const int rg   = tid / CG;
    const int row0 = blockIdx.x * 64;
    const int col0 = blockIdx.y * CPB + cg * 4;

    constexpr int VECS = 64 * KD / 4;
    for (int i = tid; i < VECS; i += 256) {
        int r  = i / (KD / 4);
        int k4 = (i % (KD / 4)) * 4;
        float4 v = make_float4(0.f, 0.f, 0.f, 0.f);
        int row = row0 + r;
        if (row < n) {
            v = *reinterpret_cast<const float4*>(A + (size_t)row * KD + k4);
            if (scA) {
                float4 sc = *reinterpret_cast<const float4*>(scA + k4);
                float4 sh = *reinterpret_cast<const float4*>(scA + KD + k4);
                v.x = fmaxf(v.x * sc.x + sh.x, 0.f);
                v.y = fmaxf(v.y * sc.y + sh.y, 0.f);
                v.z = fmaxf(v.z * sc.z + sh.z, 0.f);
                v.w = fmaxf(v.w * sc.w + sh.w, 0.f);
            }
            if (A2) {
                float4 u  = *reinterpret_cast<const float4*>(A2 + (size_t)row * KD + k4);
                float4 sc = *reinterpret_cast<const float4*>(scA2 + k4);
                float4 sh = *reinterpret_cast<const float4*>(scA2 + KD + k4);
                v.x += fmaxf(u.x * sc.x + sh.x, 0.f);
                v.y += fmaxf(u.y * sc.y + sh.y, 0.f);
                v.z += fmaxf(u.z * sc.z + sh.z, 0.f);
                v.w += fmaxf(u.w * sc.w + sh.w, 0.f);
            }
        }
        *reinterpret_cast<float4*>(&As[r][k4]) = v;
    }
    __syncthreads();

    if (col0 >= M) return;

    float acc[RPT][4];
#pragma unroll
    for (int r = 0; r < RPT; ++r)
#pragma unroll
        for (int c = 0; c < 4; ++c) acc[r][c] = 0.f;

    for (int k4 = 0; k4 < KD; k4 += 4) {
        float4 w0 = *reinterpret_cast<const float4*>(W + (size_t)(k4 + 0) * M + col0);
        float4 w1 = *reinterpret_cast<const float4*>(W + (size_t)(k4 + 1) * M + col0);
        float4 w2 = *reinterpret_cast<const float4*>(W + (size_t)(k4 + 2) * M + col0);
        float4 w3 = *reinterpret_cast<const float4*>(W + (size_t)(k4 + 3) * M + col0);
#pragma unroll
        for (int r = 0; r < RPT; ++r) {
            float4 a = *reinterpret_cast<const float4*>(&As[rg * RPT + r][k4]);
            acc[r][0] += a.x * w0.x + a.y * w1.x + a.z * w2.x + a.w * w3.x;
            acc[r][1] += a.x * w0.y + a.y * w1.y + a.z * w2.y + a.w * w3.y;
            acc[r][2] += a.x * w0.z + a.y * w1.z + a.z * w2.z + a.w * w3.z;
            acc[r][3] += a.x * w0.w + a.y * w1.w + a.z * w2.w + a.w * w3.w;
        }
    }

    float4 b = make_float4(0.f, 0.f, 0.f, 0.f);
    if (bias) b = *reinterpret_cast<const float4*>(bias + col0);
    const float w0s = C2 ? w0p[0] : 0.f;
#pragma unroll
    for (int r = 0; r < RPT; ++r) {
        int row = row0 + rg * RPT + r;
        if (row < n) {
            float4 o = make_float4(acc[r][0] + b.x, acc[r][1] + b.y,
                                   acc[r][2] + b.z, acc[r][3] + b.w);
            if (OBF) {
                // hop state in bf16 (RNE); oa keeps the fp32 w0*y term
                unsigned short* cb = reinterpret_cast<unsigned short*>(C);
                ushort4 p;
                p.x = f2bf_rne(o.x); p.y = f2bf_rne(o.y);
                p.z = f2bf_rne(o.z); p.w = f2bf_rne(o.w);
                *reinterpret_cast<ushort4*>(cb + (size_t)row * M + col0) = p;
            } else {
                *reinterpret_cast<float4*>(C + (size_t)row * M + col0) = o;
            }
            if (C2) {
                float4 q = make_float4(w0s * o.x, w0s * o.y, w0s * o.z, w0s * o.w);
                *reinterpret_cast<float4*>(C2 + (size_t)row * M + col0) = q;
            }
        }
    }
}

// ---------------- BN column stats (sum, sumsq) in double ----------------
template<int M>
__global__ __launch_bounds__(256) void colstats(const float* __restrict__ Z,
                                                double* __restrict__ st, int n) {
    constexpr int RG = 256 / M;
    const int tid = threadIdx.x;
    const int c = tid % M, rg = tid / M;
    double s = 0.0, ss = 0.0;
    for (int row = blockIdx.x * RG + rg; row < n; row += gridDim.x * RG) {
        float v = Z[(size_t)row * M + c];
        s += v;
        ss += (double)v * (double)v;
    }
    __shared__ double sh[2][256];
    sh[0][tid] = s;
    sh[1][tid] = ss;
    __syncthreads();
    if (rg == 0) {
#pragma unroll
        for (int g = 1; g < RG; ++g) { s += sh[0][c + g * M]; ss += sh[1][c + g * M]; }
        atomicAdd(&st[c], s);
        atomicAdd(&st[M + c], ss);
    }
}

__global__ void bn_finalize(const double* __restrict__ st, const float* __restrict__ g,
                            const float* __restrict__ be, float* __restrict__ scsh,
                            int M, int n) {
    int c = threadIdx.x + blockIdx.x * blockDim.x;
    if (c < M) {
        double m = st[c] / n;
        double v = st[M + c] / n - m * m;
        float scale = g[c] * rsqrtf((float)v + BN_EPS);
        scsh[c]     = scale;
        scsh[M + c] = be[c] - (float)m * scale;
    }
}

// ---------------- one propagation hop (CSR gather-sum, bf16 state) -----------
// Hop state rows are 64 bf16 = 128B. 8 lanes x 16B cover one row; 8 lane-groups
// process 8 neighbors per wave vmem instruction; x2 unrolled = 16 in flight.
// Accumulation fp32; nxt re-quantized bf16 RNE; oacc stays fp32.
__global__ __launch_bounds__(256) void propagate(
    const unsigned short* __restrict__ cur, unsigned short* __restrict__ nxt,
    float* __restrict__ oacc,
    const int* __restrict__ row_ptr, const int* __restrict__ col,
    const float* __restrict__ wts, int hop, int n) {
    const int node = blockIdx.x * 4 + (threadIdx.x >> 6);
    const int lane = threadIdx.x & 63;
    const int g = lane >> 3;      // neighbor slot 0..7
    const int l = lane & 7;       // feature oct: features l*8 .. l*8+7
    if (node >= n) return;
    const int beg = row_ptr[node], end = row_ptr[node + 1];
    float acc[8];
#pragma unroll
    for (int j = 0; j < 8; ++j) acc[j] = 0.f;

    int e = beg;
    for (; e + 16 <= end; e += 16) {
        int s0 = col[e + g];
        int s1 = col[e + g + 8];
        bf16x8 v0 = *reinterpret_cast<const bf16x8*>(cur + (size_t)s0 * DIM_P + l * 8);
        bf16x8 v1 = *reinterpret_cast<const bf16x8*>(cur + (size_t)s1 * DIM_P + l * 8);
#pragma unroll
        for (int j = 0; j < 8; ++j)
            acc[j] += bf2f((unsigned short)v0[j]) + bf2f((unsigned short)v1[j]);
    }
    if (e + 8 <= end) {
        int s = col[e + g];
        bf16x8 v = *reinterpret_cast<const bf16x8*>(cur + (size_t)s * DIM_P + l * 8);
#pragma unroll
        for (int j = 0; j < 8; ++j) acc[j] += bf2f((unsigned short)v[j]);
        e += 8;
    }
    if (e + g < end) {
        int s = col[e + g];
        bf16x8 v = *reinterpret_cast<const bf16x8*>(cur + (size_t)s * DIM_P + l * 8);
#pragma unroll
        for (int j = 0; j < 8; ++j) acc[j] += bf2f((unsigned short)v[j]);
    }

    // reduce across the 8 lane-groups (offsets 8,16,32 keep l fixed)
#pragma unroll
    for (int off = 8; off < 64; off <<= 1) {
#pragma unroll
        for (int j = 0; j < 8; ++j) acc[j] += __shfl_xor(acc[j], off, 64);
    }

    if (g == 0) {
        const size_t o = (size_t)node * DIM_P + l * 8;
        if (nxt) {
            bf16x8 ov;
#pragma unroll
            for (int j = 0; j < 8; ++j) ov[j] = (short)f2bf_rne(acc[j]);
            *reinterpret_cast<bf16x8*>(nxt + o) = ov;
        }
        const float w = wts[hop];
        float* op = oacc + o;
        float4 t0 = *reinterpret_cast<const float4*>(op);
        float4 t1 = *reinterpret_cast<const float4*>(op + 4);
        t0.x = fmaf(w, acc[0], t0.x); t0.y = fmaf(w, acc[1], t0.y);
        t0.z = fmaf(w, acc[2], t0.z); t0.w = fmaf(w, acc[3], t0.w);
        t1.x = fmaf(w, acc[4], t1.x); t1.y = fmaf(w, acc[5], t1.y);
        t1.z = fmaf(w, acc[6], t1.z); t1.w = fmaf(w, acc[7], t1.w);
        *reinterpret_cast<float4*>(op) = t0;
        *reinterpret_cast<float4*>(op + 4) = t1;
    }
}

// ---------------- Wout transpose + bf16 convert: WT[c][k] = bf16(W[k][c]) ----
// padded to OUT_PAD rows; pad rows are zero so MFMA tiles past col 999 are inert
__global__ void prep_wout(const float* __restrict__ W, unsigned short* __restrict__ WT) {
    int idx = blockIdx.x * blockDim.x + threadIdx.x;  // idx = c*64 + k
    if (idx < OUT_PAD * DIM_P) {
        int c = idx >> 6, k = idx & 63;
        WT[idx] = (c < DIM_OUT) ? f2bf_rne(W[(size_t)k * DIM_OUT + c]) : (unsigned short)0;
    }
}

// ---------------- bn3 + relu + bf16 convert, once: ABF[row][k] ----------------
__global__ void bn3_relu_bf16(const float* __restrict__ Z, const float* __restrict__ scsh,
                              unsigned short* __restrict__ O) {
    const int total8 = N_NODES * DIM_P / 8;
    int i = blockIdx.x * blockDim.x + threadIdx.x;
    if (i >= total8) return;
    int base = i * 8;
    int c = base & (DIM_P - 1);
    float4 z0 = *reinterpret_cast<const float4*>(Z + base);
    float4 z1 = *reinterpret_cast<const float4*>(Z + base + 4);
    float4 s0 = *reinterpret_cast<const float4*>(scsh + c);
    float4 s1 = *reinterpret_cast<const float4*>(scsh + c + 4);
    float4 h0 = *reinterpret_cast<const float4*>(scsh + DIM_P + c);
    float4 h1 = *reinterpret_cast<const float4*>(scsh + DIM_P + c + 4);
    bf16x8 o;
    o[0] = (short)f2bf_rne(fmaxf(z0.x * s0.x + h0.x, 0.f));
    o[1] = (short)f2bf_rne(fmaxf(z0.y * s0.y + h0.y, 0.f));
    o[2] = (short)f2bf_rne(fmaxf(z0.z * s0.z + h0.z, 0.f));
    o[3] = (short)f2bf_rne(fmaxf(z0.w * s0.w + h0.w, 0.f));
    o[4] = (short)f2bf_rne(fmaxf(z1.x * s1.x + h1.x, 0.f));
    o[5] = (short)f2bf_rne(fmaxf(z1.y * s1.y + h1.y, 0.f));
    o[6] = (short)f2bf_rne(fmaxf(z1.z * s1.z + h1.z, 0.f));
    o[7] = (short)f2bf_rne(fmaxf(z1.w * s1.w + h1.w, 0.f));
    *reinterpret_cast<bf16x8*>(O + base) = o;
}

// ---------------- final GEMM via MFMA: out = ABF @ Wout + bout ----------------
// A-operand = Wout columns (register-resident across row loop), B = node rows.
// Each lane stores float4 of 4 consecutive output columns.
__global__ __launch_bounds__(256, 4) void out_gemm_mfma(
    const unsigned short* __restrict__ ABF, const unsigned short* __restrict__ WT,
    const float* __restrict__ bout, float* __restrict__ out) {
    const int wave = threadIdx.x >> 6;
    const int lane = threadIdx.x & 63;
    const int m    = lane & 15;       // A: out-col within tile; B/D: out-row
    const int quad = lane >> 4;
    const int kb   = quad * 8;
    const int c0   = blockIdx.y * 256 + wave * 64;

    bf16x8 afrag[4][2];
    float4 bias[4];
#pragma unroll
    for (int t = 0; t < 4; ++t) {
        const unsigned short* wrow = WT + (size_t)(c0 + t * 16 + m) * DIM_P;
        afrag[t][0] = *reinterpret_cast<const bf16x8*>(wrow + kb);
        afrag[t][1] = *reinterpret_cast<const bf16x8*>(wrow + 32 + kb);
        int cc = c0 + t * 16 + quad * 4;
        bias[t] = (cc < DIM_OUT) ? *reinterpret_cast<const float4*>(bout + cc)
                                 : make_float4(0.f, 0.f, 0.f, 0.f);
    }

    const int NT = N_NODES / 16;  // 3125 row tiles
    for (int rt = blockIdx.x; rt < NT; rt += gridDim.x) {
        const int row = rt * 16 + m;
        const unsigned short* arow = ABF + (size_t)row * DIM_P;
        bf16x8 bfrag0 = *reinterpret_cast<const bf16x8*>(arow + kb);
        bf16x8 bfrag1 = *reinterpret_cast<const bf16x8*>(arow + 32 + kb);
        float* orow = out + (size_t)row * DIM_OUT;
#pragma unroll
        for (int t = 0; t < 4; ++t) {
            floatx4 acc = {0.f, 0.f, 0.f, 0.f};
            acc = __builtin_amdgcn_mfma_f32_16x16x32_bf16(afrag[t][0], bfrag0, acc, 0, 0, 0);
            acc = __builtin_amdgcn_mfma_f32_16x16x32_bf16(afrag[t][1], bfrag1, acc, 0, 0, 0);
            int cc = c0 + t * 16 + quad * 4;
            if (cc < DIM_OUT) {
                float4 o = make_float4(acc[0] + bias[t].x, acc[1] + bias[t].y,
                                       acc[2] + bias[t].z, acc[3] + bias[t].w);
                *reinterpret_cast<float4*>(orow + cc) = o;
            }
        }
    }
}

// ---------------- launch ----------------
extern "C" void kernel_launch(void* const* d_in, const int* in_sizes, int n_in,
                              void* d_out, int out_size, void* d_ws, size_t ws_size,
                              hipStream_t stream) {
    const float* x    = (const float*)d_in[0];
    const int*   ei   = (const int*)  d_in[1];
    const float* W1   = (const float*)d_in[2];
    const float* g1   = (const float*)d_in[4];
    const float* be1  = (const float*)d_in[5];
    const float* W2   = (const float*)d_in[6];
    const float* g2   = (const float*)d_in[8];
    const float* be2  = (const float*)d_in[9];
    const float* att  = (const float*)d_in[10];
    const float* W3   = (const float*)d_in[11];
    const float* g3   = (const float*)d_in[13];
    const float* be3  = (const float*)d_in[14];
    const float* Wout = (const float*)d_in[15];
    const float* bout = (const float*)d_in[16];
    float* out = (float*)d_out;

    char* base = (char*)d_ws;
    size_t off = 0;
    auto alloc = [&](size_t bytes) -> void* {
        void* r = base + off;
        off += (bytes + 255) & ~(size_t)255;
        return r;
    };
    float*  f0      = (float*) alloc((size_t)N_NODES * DIM_H * 4); // z1
    float*  f1      = (float*) alloc((size_t)N_NODES * DIM_H * 4); // z2
    unsigned short* yb = (unsigned short*)alloc((size_t)N_NODES * DIM_P * 2); // bf16 hop ping
    unsigned short* tb = (unsigned short*)alloc((size_t)N_NODES * DIM_P * 2); // bf16 hop pong
    float*  oa      = (float*) alloc((size_t)N_NODES * DIM_P * 4); // fp32 weighted acc
    double* st      = (double*)alloc(640 * 8);
    float*  scsh    = (float*) alloc(768 * 4);
    float*  wts     = (float*) alloc(16 * 4);
    int*    row_ptr = (int*)   alloc((size_t)(N_NODES + 1) * 4);
    int*    deg     = (int*)   alloc((size_t)N_NODES * 4);   // degree -> cursor
    int*    col     = (int*)   alloc((size_t)N_EDGES * 4);
    int*    bsums   = (int*)   alloc(64 * 4);
    unsigned short* WT  = (unsigned short*)alloc((size_t)OUT_PAD * DIM_P * 2);
    unsigned short* ABF = (unsigned short*)alloc((size_t)N_NODES * DIM_P * 2);

    const int* src = ei;
    const int* dst = ei + N_EDGES;
    double* st1 = st;   double* st2 = st + 256; double* st3 = st + 512;
    float*  sc1 = scsh; float*  sc2 = scsh + 256; float* sc3 = scsh + 512;

    hipMemsetAsync(st, 0, 640 * 8, stream);
    hipMemsetAsync(deg, 0, (size_t)N_NODES * 4, stream);

    softmax11<<<1, 64, 0, stream>>>(att, wts);
    prep_wout<<<ceil_div(OUT_PAD * DIM_P, 256), 256, 0, stream>>>(Wout, WT);

    // CSR by destination (fast 3-stage scan)
    count_deg<<<ceil_div(N_EDGES, 256), 256, 0, stream>>>(dst, deg, N_EDGES);
    const int NB = ceil_div(N_NODES, 1024);
    scan_local<<<NB, 1024, 0, stream>>>(deg, row_ptr, bsums, N_NODES);
    scan_bsums<<<1, 64, 0, stream>>>(bsums, NB);
    scan_finish<<<ceil_div(N_NODES, 256), 256, 0, stream>>>(row_ptr, deg, bsums, N_NODES);
    fill_csr<<<ceil_div(N_EDGES, 256), 256, 0, stream>>>(src, dst, deg, col, N_EDGES);

    const int RB = ceil_div(N_NODES, 64);

    // layer 1: z1 = x@W1 (b1 cancels in BN)
    gemm_fused<128, 128, false><<<dim3(RB, 1), 256, 0, stream>>>(
        x, nullptr, nullptr, nullptr, W1, nullptr, f0, nullptr, nullptr, N_NODES, DIM_H);
    colstats<128><<<256, 256, 0, stream>>>(f0, st1, N_NODES);
    bn_finalize<<<1, 128, 0, stream>>>(st1, g1, be1, sc1, 128, N_NODES);

    // layer 2: z2 = relu(bn1(z1)) @ W2  (bn1+relu fused into A-staging)
    gemm_fused<128, 128, false><<<dim3(RB, 1), 256, 0, stream>>>(
        f0, sc1, nullptr, nullptr, W2, nullptr, f1, nullptr, nullptr, N_NODES, DIM_H);
    colstats<128><<<256, 256, 0, stream>>>(f1, st2, N_NODES);
    bn_finalize<<<1, 128, 0, stream>>>(st2, g2, be2, sc2, 128, N_NODES);

    // layer 3 input: h2 = relu(bn2(z2)) + relu(bn1(z1)); y = h2@W3.
    // C -> yb (bf16 hop state), C2 -> oa = w0*y (fp32, unquantized hop-0 term)
    gemm_fused<128, 64, true><<<dim3(RB, 1), 256, 0, stream>>>(
        f1, sc2, f0, sc1, W3, nullptr, (float*)yb, oa, wts, N_NODES, DIM_P);

    // 10 hops, bf16 state (half the gather bytes of fp32), launch per hop
    {
        unsigned short* cur = yb;
        unsigned short* nxt = tb;
        for (int hop = 1; hop <= KHOPS; ++hop) {
            propagate<<<ceil_div(N_NODES, 4), 256, 0, stream>>>(
                cur, (hop == KHOPS) ? nullptr : nxt, oa, row_ptr, col, wts, hop, N_NODES);
            unsigned short* t = cur; cur = nxt; nxt = t;
        }
    }

    // layer 3 BN stats (b3 cancels); then bn3+relu+bf16 applied ONCE
    colstats<64><<<256, 256, 0, stream>>>(oa, st3, N_NODES);
    bn_finalize<<<1, 64, 0, stream>>>(st3, g3, be3, sc3, 64, N_NODES);
    bn3_relu_bf16<<<ceil_div(N_NODES * DIM_P / 8, 256), 256, 0, stream>>>(oa, sc3, ABF);

    // output: out = ABF @ Wout + bout   (bf16 MFMA, column-persistent waves)
    out_gemm_mfma<<<dim3(512, 4), 256, 0, stream>>>(ABF, WT, bout, out);
}